// Round 3
// baseline (249.923 us; speedup 1.0000x reference)
//
#include <hip/hip_runtime.h>
#include <hip/hip_bf16.h>
#include <stdint.h>
#include <stddef.h>

typedef __attribute__((ext_vector_type(8))) short short8;
typedef __attribute__((ext_vector_type(4))) float f32x4;
typedef __attribute__((ext_vector_type(16))) float f32x16;

#define MFMA16(a, b, c) __builtin_amdgcn_mfma_f32_16x16x32_bf16((a), (b), (c), 0, 0, 0)
#define MFMA32(a, b, c) __builtin_amdgcn_mfma_f32_32x32x16_bf16((a), (b), (c), 0, 0, 0)

// Q pre-scale: HEAD_DIM^-0.5 * log2(e); flash uses raw v_exp_f32 (exp2)
#define QSCALE 0.1803368801111204f

#if __has_builtin(__builtin_amdgcn_exp2f)
#define EXP2(x) __builtin_amdgcn_exp2f(x)
#else
#define EXP2(x) __builtin_exp2f(x)
#endif

__device__ __forceinline__ float b2f(short x) {
    unsigned u = ((unsigned)(unsigned short)x) << 16;
    float f; __builtin_memcpy(&f, &u, 4); return f;
}
// round-nearest-even f32->bf16 (scalar)
__device__ __forceinline__ short f2b(float f) {
    unsigned u; __builtin_memcpy(&u, &f, 4);
    u = (u + 0x7FFFu + ((u >> 16) & 1u)) >> 16;
    return (short)u;
}
// two f32 -> packed bf16x2 in 3 VALU (2 adds + v_perm), round-half-up.
__device__ __forceinline__ unsigned pack2(float a, float b) {
    unsigned ua, ub; __builtin_memcpy(&ua, &a, 4); __builtin_memcpy(&ub, &b, 4);
    return __builtin_amdgcn_perm(ub + 0x8000u, ua + 0x8000u, 0x07060302u);
}
// two f32 -> packed bf16x2 in ONE VALU (RNE). Same lo/hi order as pack2.
__device__ __forceinline__ unsigned cvtpk(float a, float b) {
    unsigned r;
    asm("v_cvt_pk_bf16_f32 %0, %1, %2" : "=v"(r) : "v"(a), "v"(b));
    return r;
}
// 8 contiguous f32 -> bf16x8 (RNE)
__device__ __forceinline__ short8 load8f(const float* p) {
    const float4 f0 = *(const float4*)p;
    const float4 f1 = *(const float4*)(p + 4);
    short8 r;
    r[0]=f2b(f0.x); r[1]=f2b(f0.y); r[2]=f2b(f0.z); r[3]=f2b(f0.w);
    r[4]=f2b(f1.x); r[5]=f2b(f1.y); r[6]=f2b(f1.z); r[7]=f2b(f1.w);
    return r;
}

// ---------------------------------------------------------------------------
// Fused f32->bf16 converter for up to 3 arrays. nX = elems/8.
// ---------------------------------------------------------------------------
__global__ __launch_bounds__(256) void cvt3(
    const float* __restrict__ s0, short* __restrict__ d0, int n0,
    const float* __restrict__ s1, short* __restrict__ d1, int n1,
    const float* __restrict__ s2, short* __restrict__ d2, int n2)
{
    int i = blockIdx.x * 256 + threadIdx.x;
    if (i < n0) { *(short8*)(d0 + (size_t)i * 8) = load8f(s0 + (size_t)i * 8); return; }
    i -= n0;
    if (i < n1) { *(short8*)(d1 + (size_t)i * 8) = load8f(s1 + (size_t)i * 8); return; }
    i -= n1;
    if (i < n2) { *(short8*)(d2 + (size_t)i * 8) = load8f(s2 + (size_t)i * 8); }
}

// ---------------------------------------------------------------------------
// Fused QKV GEMM (bf16 in/out). Grid (64,12): sec = y>>2 (0=Q,1=K,2=V).
//   Q (x QSCALE) -> Qb[bh][seq][64];  K -> Kb[bh][seq][64]
//   V -> Vb[bh][64][seq] via LDS-transposed epilogue (coalesced b128 stores)
// ---------------------------------------------------------------------------
__global__ __launch_bounds__(256) void qkv_gemm(
    const short* __restrict__ X, const short* __restrict__ W,
    const float* __restrict__ bias,
    short* __restrict__ Qb, short* __restrict__ Kb, short* __restrict__ Vb)
{
    __shared__ short sT[128][132];

    const int tid  = threadIdx.x;
    const int wv   = tid >> 6;
    const int lane = tid & 63;
    const int l15  = lane & 15;
    const int quad = lane >> 4;
    const int m0   = blockIdx.x * 128 + (wv >> 1) * 64;
    const int sec  = blockIdx.y >> 2;
    const int bis  = blockIdx.y & 3;
    const int nbase = sec * 512 + bis * 128;
    const int j0   = (wv & 1) * 64;

    const f32x4 zero = {0.f, 0.f, 0.f, 0.f};
    f32x4 acc[4][4];
#pragma unroll
    for (int i = 0; i < 4; i++)
#pragma unroll
        for (int j = 0; j < 4; j++) acc[i][j] = zero;

    for (int k0 = 0; k0 < 512; k0 += 32) {
        short8 a[4], b[4];
#pragma unroll
        for (int i = 0; i < 4; i++)
            a[i] = *(const short8*)(X + (size_t)(m0 + i * 16 + l15) * 512 + k0 + quad * 8);
#pragma unroll
        for (int j = 0; j < 4; j++)
            b[j] = *(const short8*)(W + (size_t)(nbase + j0 + j * 16 + l15) * 512 + k0 + quad * 8);
#pragma unroll
        for (int i = 0; i < 4; i++)
#pragma unroll
            for (int j = 0; j < 4; j++)
                acc[i][j] = MFMA16(a[i], b[j], acc[i][j]);
    }

    if (sec < 2) {
        const float scale = (sec == 0) ? QSCALE : 1.0f;
        short* dst = (sec == 0) ? Qb : Kb;
#pragma unroll
        for (int j = 0; j < 4; j++) {
            const int jc = bis * 128 + j0 + j * 16 + l15;   // 0..511 in section
            const float bs = bias[sec * 512 + jc];
            const int hl = jc >> 6, d = jc & 63;
#pragma unroll
            for (int i = 0; i < 4; i++) {
#pragma unroll
                for (int r = 0; r < 4; r++) {
                    const int m = m0 + i * 16 + quad * 4 + r;
                    const int bb = m >> 12, seq = m & 4095;
                    dst[((size_t)(bb * 8 + hl) * 4096 + seq) * 64 + d] =
                        f2b((acc[i][j][r] + bs) * scale);
                }
            }
        }
    } else {
        // V: pack 4 consecutive seq into b64 LDS writes, then coalesced b128
#pragma unroll
        for (int j = 0; j < 4; j++) {
            const int jcl = j0 + j * 16 + l15;             // 0..127
            const float bs = bias[nbase + jcl];
#pragma unroll
            for (int i = 0; i < 4; i++) {
                uint2 w;
                w.x = pack2(acc[i][j][0] + bs, acc[i][j][1] + bs);
                w.y = pack2(acc[i][j][2] + bs, acc[i][j][3] + bs);
                *(uint2*)&sT[jcl][(wv >> 1) * 64 + i * 16 + quad * 4] = w;
            }
        }
        __syncthreads();

        const int jcl = tid >> 1, half = tid & 1;
        const int hl = (bis * 128 + jcl) >> 6;
        const int d  = jcl & 63;
        const int bb = (blockIdx.x * 128) >> 12;
        const int seq0 = ((blockIdx.x * 128) & 4095) + half * 64;
        short* dst = Vb + ((size_t)(bb * 8 + hl) * 64 + d) * 4096 + seq0;
#pragma unroll
        for (int u = 0; u < 8; u++)
            *(short8*)(dst + u * 8) = *(const short8*)&sT[jcl][half * 64 + u * 8];
    }
}

// ---------------------------------------------------------------------------
// Flash attention, r20: r19's dbuf/one-barrier structure +
//  (1) 2-DEEP ST SOFTWARE PIPELINE (T15): QK MFMAs of subtile c+1 issue
//      before exp/pack/PV of subtile c (static stA/stB names — no runtime
//      indexing). MFMA pipe (QK[c+1] + PV[c]) overlaps VALU (exp/pack[c])
//      WITHIN the wave; r19's VGPR=64 schedule couldn't hold 2 STs.
//  (2) o2 ones-MFMA dropped (-8 MFMA32/tile = -20% MFMA work); lsum via
//      VALU TREE (4 independent accumulators, no serial chain) + one
//      epilogue __shfl_xor. Frees 16 VGPRs for (1).
//  (3) pack2 (3 VALU) -> v_cvt_pk_bf16_f32 (1 VALU) for the P->bf16 pack.
// V stored with key-index bits 2<->3 swapped (involution) so the PV
// B-fragment is the lane's own exp'd S^T registers (r18, verified).
// Split-K=2 partials (no-max streaming softmax): O = (l0*O0+l1*O1)/(l0+l1).
// ---------------------------------------------------------------------------
__device__ __forceinline__ f32x16 qk_tile(const short (*sKc)[72], int c,
                                          int l31, int half, const short8* aq)
{
    f32x16 st = {};
    __builtin_amdgcn_s_setprio(1);
#pragma unroll
    for (int s = 0; s < 4; s++) {
        const short8 bk = *(const short8*)&sKc[c * 32 + l31][s * 16 + half * 8];
        st = MFMA32(bk, aq[s], st);
    }
    __builtin_amdgcn_s_setprio(0);
    return st;
}

__device__ __forceinline__ void pv_tile(const short (*sVc)[136], int c,
                                        int l31, int half, const f32x16& st,
                                        f32x16& o0, f32x16& o1,
                                        float& la0, float& la1, float& la2, float& la3)
{
    float e[16];
#pragma unroll
    for (int r = 0; r < 16; r++) e[r] = EXP2(st[r]);
    la0 += (e[0] + e[1]) + (e[2] + e[3]);
    la1 += (e[4] + e[5]) + (e[6] + e[7]);
    la2 += (e[8] + e[9]) + (e[10] + e[11]);
    la3 += (e[12] + e[13]) + (e[14] + e[15]);
    uint4 w0 = { cvtpk(e[0], e[1]),   cvtpk(e[2], e[3]),
                 cvtpk(e[4], e[5]),   cvtpk(e[6], e[7]) };
    uint4 w1 = { cvtpk(e[8], e[9]),   cvtpk(e[10], e[11]),
                 cvtpk(e[12], e[13]), cvtpk(e[14], e[15]) };
    const short8 bp0 = *(const short8*)&w0;   // PV B-frag, step t=2c
    const short8 bp1 = *(const short8*)&w1;   // step t=2c+1

    __builtin_amdgcn_s_setprio(1);
    const short8 bv00 = *(const short8*)&sVc[l31][(2 * c) * 16 + half * 8];
    const short8 bv01 = *(const short8*)&sVc[32 + l31][(2 * c) * 16 + half * 8];
    o0 = MFMA32(bv00, bp0, o0);
    o1 = MFMA32(bv01, bp0, o1);
    const short8 bv10 = *(const short8*)&sVc[l31][(2 * c + 1) * 16 + half * 8];
    const short8 bv11 = *(const short8*)&sVc[32 + l31][(2 * c + 1) * 16 + half * 8];
    o0 = MFMA32(bv10, bp1, o0);
    o1 = MFMA32(bv11, bp1, o1);
    __builtin_amdgcn_s_setprio(0);
}

__global__ __launch_bounds__(512, 4) void flash_attn(
    const short* __restrict__ Q, const short* __restrict__ K,
    const short* __restrict__ V, short* __restrict__ PO0,
    short* __restrict__ PO1, float* __restrict__ lbuf, int niter)
{
    __shared__ short sK[2][128][72];     // [buf][key][d], +8 pad
    __shared__ short sV[2][64][136];     // [buf][d][key-bitswapped], +8 pad

    const int tid  = threadIdx.x;
    const int wv   = tid >> 6;            // 0..7
    const int lane = tid & 63;
    const int l31  = lane & 31;
    const int half = lane >> 5;           // 0/1
    const int bh = blockIdx.y;
    const int b = bh >> 3, h = bh & 7;
    const int qw = blockIdx.x * 256 + wv * 32;   // wave's 32 queries
    const int ks = blockIdx.z;
    const int key0 = ks * niter * 128;

    const short* Qb = Q + (size_t)bh * 4096 * 64;
    const short* Kb = K + (size_t)bh * 4096 * 64;
    const short* Vb = V + (size_t)bh * 64 * 4096;

    // Q B-frags: B[k=d][n=query l31]; step s covers d = s*16 + half*8 + j
    short8 aq[4];
#pragma unroll
    for (int s = 0; s < 4; s++)
        aq[s] = *(const short8*)(Qb + (size_t)(qw + l31) * 64 + s * 16 + half * 8);

    f32x16 o0 = {}, o1 = {};              // O^T acc, d-tiles 0/1 (col=query)
    float la0 = 0.f, la1 = 0.f, la2 = 0.f, la3 = 0.f;   // lsum tree partials

    // staging: 512 threads x (2 K-chunks + 2 V-chunks) per 128-key tile
    const int r0  = tid >> 3;             // 0..63
    const int scb = (tid & 7) * 8;        // 0..56
    const int vb  = (scb & ~12) | ((scb & 8) >> 1);  // bit2<->bit3 swap base

    short8 pk0, pk1, pv0, pv1;
    // tile 0 -> buf 0 (no barrier needed yet: LDS untouched)
    pk0 = *(const short8*)(Kb + (size_t)(key0 + r0) * 64 + scb);
    pk1 = *(const short8*)(Kb + (size_t)(key0 + 64 + r0) * 64 + scb);
    pv0 = *(const short8*)(Vb + (size_t)r0 * 4096 + key0 + scb);
    pv1 = *(const short8*)(Vb + (size_t)r0 * 4096 + key0 + 64 + scb);
    *(short8*)&sK[0][r0][scb]      = pk0;
    *(short8*)&sK[0][64 + r0][scb] = pk1;
    *(uint2*)&sV[0][r0][vb]          = ((const uint2*)&pv0)[0];
    *(uint2*)&sV[0][r0][vb + 8]      = ((const uint2*)&pv0)[1];
    *(uint2*)&sV[0][r0][64 + vb]     = ((const uint2*)&pv1)[0];
    *(uint2*)&sV[0][r0][64 + vb + 8] = ((const uint2*)&pv1)[1];
    // prefetch tile 1 into regs
    {
        const int kn = key0 + 128;
        pk0 = *(const short8*)(Kb + (size_t)(kn + r0) * 64 + scb);
        pk1 = *(const short8*)(Kb + (size_t)(kn + 64 + r0) * 64 + scb);
        pv0 = *(const short8*)(Vb + (size_t)r0 * 4096 + kn + scb);
        pv1 = *(const short8*)(Vb + (size_t)r0 * 4096 + kn + 64 + scb);
    }

    for (int kt = 0; kt < niter; ++kt) {
        __syncthreads();   // buf[kt&1] writes visible; prev reads of buf[(kt+1)&1] done

        if (kt + 1 < niter) {          // write tile kt+1 to the other buffer
            short (*sKn)[72]  = sK[(kt + 1) & 1];
            short (*sVn)[136] = sV[(kt + 1) & 1];
            *(short8*)&sKn[r0][scb]      = pk0;
            *(short8*)&sKn[64 + r0][scb] = pk1;
            *(uint2*)&sVn[r0][vb]          = ((const uint2*)&pv0)[0];
            *(uint2*)&sVn[r0][vb + 8]      = ((const uint2*)&pv0)[1];
            *(uint2*)&sVn[r0][64 + vb]     = ((const uint2*)&pv1)[0];
            *(uint2*)&sVn[r0][64 + vb + 8] = ((const uint2*)&pv1)[1];
        }
        if (kt + 2 < niter) {          // issue global loads for tile kt+2
            const int kn = key0 + (kt + 2) * 128;
            pk0 = *(const short8*)(Kb + (size_t)(kn + r0) * 64 + scb);
            pk1 = *(const short8*)(Kb + (size_t)(kn + 64 + r0) * 64 + scb);
            pv0 = *(const short8*)(Vb + (size_t)r0 * 4096 + kn + scb);
            pv1 = *(const short8*)(Vb + (size_t)r0 * 4096 + kn + 64 + scb);
        }

        const short (*sKc)[72]  = sK[kt & 1];
        const short (*sVc)[136] = sV[kt & 1];

        // 2-deep pipeline over 4 c-subtiles: QK(c+1) overlaps exp/pack/PV(c)
        f32x16 stA = qk_tile(sKc, 0, l31, half, aq);
        f32x16 stB = qk_tile(sKc, 1, l31, half, aq);
        pv_tile(sVc, 0, l31, half, stA, o0, o1, la0, la1, la2, la3);
        stA = qk_tile(sKc, 2, l31, half, aq);
        pv_tile(sVc, 1, l31, half, stB, o0, o1, la0, la1, la2, la3);
        stB = qk_tile(sKc, 3, l31, half, aq);
        pv_tile(sVc, 2, l31, half, stA, o0, o1, la0, la1, la2, la3);
        pv_tile(sVc, 3, l31, half, stB, o0, o1, la0, la1, la2, la3);
    }

    // lane's half-row sum; partner half (lane^32) holds the other 16 keys/c
    float lsum = (la0 + la1) + (la2 + la3);
    lsum += __shfl_xor(lsum, 32);
    const float inv = 1.f / fmaxf(lsum, 1e-30f);

    short* PO = (ks == 0) ? PO0 : PO1;
    // O^T: reg-quad q = 4 consecutive d at 8q + 4*half (+32 for o1), query l31
#pragma unroll
    for (int q = 0; q < 4; q++) {
        uint2 w0, w1;
        w0.x = pack2(o0[4 * q + 0] * inv, o0[4 * q + 1] * inv);
        w0.y = pack2(o0[4 * q + 2] * inv, o0[4 * q + 3] * inv);
        w1.x = pack2(o1[4 * q + 0] * inv, o1[4 * q + 1] * inv);
        w1.y = pack2(o1[4 * q + 2] * inv, o1[4 * q + 3] * inv);
        const size_t rowoff = ((size_t)b * 4096 + qw + l31) * 512;
        const int col = h * 64 + q * 8 + half * 4;
        *(uint2*)(PO + rowoff + col) = w0;
        *(uint2*)(PO + rowoff + col + 32) = w1;
    }
    if (half == 0)
        lbuf[((size_t)ks * 16 + bh) * 4096 + qw + l31] = lsum;
}

// ---------------------------------------------------------------------------
// Combine the 2 key-split partials: attn(ws) = (l0*O0 + l1*O1)/(l0+l1).
// ---------------------------------------------------------------------------
__global__ __launch_bounds__(256) void combine(
    const short* __restrict__ PO0, const short* __restrict__ PO1,
    short* __restrict__ attn, const float* __restrict__ L)
{
    const int i = blockIdx.x * 256 + threadIdx.x;   // 0..524287
    const size_t flat = (size_t)i * 8;
    const int col = (int)(flat & 511);
    const int q   = (int)((flat >> 9) & 4095);
    const int b   = (int)(flat >> 21);
    const int bh  = b * 8 + (col >> 6);
    const float l0 = L[(size_t)bh * 4096 + q];
    const float l1 = L[(size_t)65536 + (size_t)bh * 4096 + q];
    const float inv = 1.f / (l0 + l1);
    const float w0 = l0 * inv, w1 = l1 * inv;
    const short8 a = *(const short8*)(PO0 + flat);
    const short8 c = *(const short8*)(PO1 + flat);
    short8 r;
#pragma unroll
    for (int k = 0; k < 8; k += 2) {
        const unsigned p = pack2(w0 * b2f(a[k]) + w1 * b2f(c[k]),
                                 w0 * b2f(a[k + 1]) + w1 * b2f(c[k + 1]));
        r[k]     = (short)(p & 0xFFFF);
        r[k + 1] = (short)(p >> 16);
    }
    *(short8*)(attn + flat) = r;
}

// ---------------------------------------------------------------------------
// Projection, single full-GPU launch: grid (64,4) = 256 blocks.
// ---------------------------------------------------------------------------
__global__ __launch_bounds__(256) void proj_gemm(
    const short* __restrict__ A, const short* __restrict__ W,
    const float* __restrict__ bias, float* __restrict__ dst)
{
    const int tid  = threadIdx.x;
    const int wv   = tid >> 6;
    const int lane = tid & 63;
    const int l15  = lane & 15;
    const int quad = lane >> 4;
    const int m0 = blockIdx.x * 128 + (wv >> 1) * 64;   // 0..8191
    const int n0 = blockIdx.y * 128 + (wv & 1) * 64;

    const f32x4 zero = {0.f, 0.f, 0.f, 0.f};
    f32x4 acc[4][4];
#pragma unroll
    for (int i = 0; i < 4; i++)
#pragma unroll
        for (int j = 0; j < 4; j++) acc[i][j] = zero;

    for (int k0 = 0; k0 < 512; k0 += 32) {
        short8 a[4], b[4];
#pragma unroll
        for (int i = 0; i < 4; i++)
            a[i] = *(const short8*)(A + (size_t)(m0 + i * 16 + l15) * 512 + k0 + quad * 8);
#pragma unroll
        for (int j = 0; j < 4; j++)
            b[j] = *(const short8*)(W + (size_t)(n0 + j * 16 + l15) * 512 + k0 + quad * 8);
#pragma unroll
        for (int i = 0; i < 4; i++)
#pragma unroll
            for (int j = 0; j < 4; j++)
                acc[i][j] = MFMA16(a[i], b[j], acc[i][j]);
    }

#pragma unroll
    for (int j = 0; j < 4; j++) {
        const int n = n0 + j * 16 + l15;
        const float bs = bias[n];
#pragma unroll
        for (int i = 0; i < 4; i++) {
#pragma unroll
            for (int r = 0; r < 4; r++) {
                const int m = m0 + i * 16 + quad * 4 + r;
                dst[(size_t)m * 512 + n] = acc[i][j][r] + bs;
            }
        }
    }
}

// ---------------------------------------------------------------------------
// Memory plan (ws >= 25 MB, proven). 5 dispatches:
//   d_out [0,8M):    xb -> PO0 (flash split 0) -> proj output [0,8M)
//   d_out [8M,9.5M): wb (dead after qkv)
//   d_out [8M,16M):  PO1 (flash split 1) -> proj output [8M,16M)
//   ws [0,8M):  Qf -> attn (combine output; Qf dead after flash)
//   ws [8M,16M) Kf | [16M,24M) Vf | [24M,24.5M) lbuf | [24.5M,25M) pwb
// ---------------------------------------------------------------------------
extern "C" void kernel_launch(void* const* d_in, const int* in_sizes, int n_in,
                              void* d_out, int out_size, void* d_ws, size_t ws_size,
                              hipStream_t stream)
{
    const float* x      = (const float*)d_in[0];   // [2,4096,512] f32
    const float* qkv_w  = (const float*)d_in[1];   // [1536,512]   f32
    const float* qkv_b  = (const float*)d_in[2];   // [1536]       f32
    const float* proj_w = (const float*)d_in[3];   // [512,512]    f32
    const float* proj_b = (const float*)d_in[4];   // [512]        f32

    const size_t MB = 1024 * 1024;
    short* xb   = (short*)d_out;
    short* wb   = (short*)d_out + 4 * MB;
    short* PO0  = (short*)d_out;                   // [0,8M) after xb dies
    short* PO1  = (short*)d_out + 4 * MB;          // [8M,16M) after wb dies
    float* out  = (float*)d_out;

    short* Qf = (short*)d_ws;
    short* Kf = Qf + (size_t)16 * 4096 * 64;
    short* Vf = Kf + (size_t)16 * 4096 * 64;       // [bh][64][4096]
    short* attn = Qf;                              // ws [0,8M), post-flash life
    float* lbuf = (float*)((char*)d_ws + 24 * MB);
    short* pwb  = (short*)((char*)d_ws + 24 * MB + 512 * 1024);

    cvt3<<<2560, 256, 0, stream>>>(x, xb, 524288, qkv_w, wb, 98304, proj_w, pwb, 32768);
    qkv_gemm<<<dim3(64, 12), 256, 0, stream>>>(xb, wb, qkv_b, Qf, Kf, Vf);
    flash_attn<<<dim3(16, 16, 2), 512, 0, stream>>>(Qf, Kf, Vf, PO0, PO1, lbuf, 16);
    combine<<<2048, 256, 0, stream>>>(PO0, PO1, attn, lbuf);
    proj_gemm<<<dim3(64, 4), 256, 0, stream>>>(attn, pwb, proj_b, out);
}

// Round 4
// 246.772 us; speedup vs baseline: 1.0128x; 1.0128x over previous
//
#include <hip/hip_runtime.h>
#include <hip/hip_bf16.h>
#include <stdint.h>
#include <stddef.h>

typedef __attribute__((ext_vector_type(8))) short short8;
typedef __attribute__((ext_vector_type(4))) float f32x4;
typedef __attribute__((ext_vector_type(16))) float f32x16;

#define MFMA16(a, b, c) __builtin_amdgcn_mfma_f32_16x16x32_bf16((a), (b), (c), 0, 0, 0)
#define MFMA32(a, b, c) __builtin_amdgcn_mfma_f32_32x32x16_bf16((a), (b), (c), 0, 0, 0)

// Q pre-scale: HEAD_DIM^-0.5 * log2(e); flash uses raw v_exp_f32 (exp2)
#define QSCALE 0.1803368801111204f

#if __has_builtin(__builtin_amdgcn_exp2f)
#define EXP2(x) __builtin_amdgcn_exp2f(x)
#else
#define EXP2(x) __builtin_exp2f(x)
#endif

__device__ __forceinline__ float b2f(short x) {
    unsigned u = ((unsigned)(unsigned short)x) << 16;
    float f; __builtin_memcpy(&f, &u, 4); return f;
}
// round-nearest-even f32->bf16 (scalar)
__device__ __forceinline__ short f2b(float f) {
    unsigned u; __builtin_memcpy(&u, &f, 4);
    u = (u + 0x7FFFu + ((u >> 16) & 1u)) >> 16;
    return (short)u;
}
// two f32 -> packed bf16x2 in 3 VALU (2 adds + v_perm), round-half-up.
__device__ __forceinline__ unsigned pack2(float a, float b) {
    unsigned ua, ub; __builtin_memcpy(&ua, &a, 4); __builtin_memcpy(&ub, &b, 4);
    return __builtin_amdgcn_perm(ub + 0x8000u, ua + 0x8000u, 0x07060302u);
}
// two f32 -> packed bf16x2 in ONE VALU (RNE). Same lo/hi order as pack2.
__device__ __forceinline__ unsigned cvtpk(float a, float b) {
    unsigned r;
    asm("v_cvt_pk_bf16_f32 %0, %1, %2" : "=v"(r) : "v"(a), "v"(b));
    return r;
}
// 8 contiguous f32 -> bf16x8 (RNE)
__device__ __forceinline__ short8 load8f(const float* p) {
    const float4 f0 = *(const float4*)p;
    const float4 f1 = *(const float4*)(p + 4);
    short8 r;
    r[0]=f2b(f0.x); r[1]=f2b(f0.y); r[2]=f2b(f0.z); r[3]=f2b(f0.w);
    r[4]=f2b(f1.x); r[5]=f2b(f1.y); r[6]=f2b(f1.z); r[7]=f2b(f1.w);
    return r;
}

// ---------------------------------------------------------------------------
// Fused f32->bf16 converter for up to 3 arrays. nX = elems/8.
// ---------------------------------------------------------------------------
__global__ __launch_bounds__(256) void cvt3(
    const float* __restrict__ s0, short* __restrict__ d0, int n0,
    const float* __restrict__ s1, short* __restrict__ d1, int n1,
    const float* __restrict__ s2, short* __restrict__ d2, int n2)
{
    int i = blockIdx.x * 256 + threadIdx.x;
    if (i < n0) { *(short8*)(d0 + (size_t)i * 8) = load8f(s0 + (size_t)i * 8); return; }
    i -= n0;
    if (i < n1) { *(short8*)(d1 + (size_t)i * 8) = load8f(s1 + (size_t)i * 8); return; }
    i -= n1;
    if (i < n2) { *(short8*)(d2 + (size_t)i * 8) = load8f(s2 + (size_t)i * 8); }
}

// ---------------------------------------------------------------------------
// Fused QKV GEMM (bf16 in/out). Grid (64,12): sec = y>>2 (0=Q,1=K,2=V).
//   Q (x QSCALE) -> Qb[bh][seq][64];  K -> Kb[bh][seq][64]
//   V -> Vb[bh][64][seq] via LDS-transposed epilogue (coalesced b128 stores)
// ---------------------------------------------------------------------------
__global__ __launch_bounds__(256) void qkv_gemm(
    const short* __restrict__ X, const short* __restrict__ W,
    const float* __restrict__ bias,
    short* __restrict__ Qb, short* __restrict__ Kb, short* __restrict__ Vb)
{
    __shared__ short sT[128][132];

    const int tid  = threadIdx.x;
    const int wv   = tid >> 6;
    const int lane = tid & 63;
    const int l15  = lane & 15;
    const int quad = lane >> 4;
    const int m0   = blockIdx.x * 128 + (wv >> 1) * 64;
    const int sec  = blockIdx.y >> 2;
    const int bis  = blockIdx.y & 3;
    const int nbase = sec * 512 + bis * 128;
    const int j0   = (wv & 1) * 64;

    const f32x4 zero = {0.f, 0.f, 0.f, 0.f};
    f32x4 acc[4][4];
#pragma unroll
    for (int i = 0; i < 4; i++)
#pragma unroll
        for (int j = 0; j < 4; j++) acc[i][j] = zero;

    for (int k0 = 0; k0 < 512; k0 += 32) {
        short8 a[4], b[4];
#pragma unroll
        for (int i = 0; i < 4; i++)
            a[i] = *(const short8*)(X + (size_t)(m0 + i * 16 + l15) * 512 + k0 + quad * 8);
#pragma unroll
        for (int j = 0; j < 4; j++)
            b[j] = *(const short8*)(W + (size_t)(nbase + j0 + j * 16 + l15) * 512 + k0 + quad * 8);
#pragma unroll
        for (int i = 0; i < 4; i++)
#pragma unroll
            for (int j = 0; j < 4; j++)
                acc[i][j] = MFMA16(a[i], b[j], acc[i][j]);
    }

    if (sec < 2) {
        const float scale = (sec == 0) ? QSCALE : 1.0f;
        short* dst = (sec == 0) ? Qb : Kb;
#pragma unroll
        for (int j = 0; j < 4; j++) {
            const int jc = bis * 128 + j0 + j * 16 + l15;   // 0..511 in section
            const float bs = bias[sec * 512 + jc];
            const int hl = jc >> 6, d = jc & 63;
#pragma unroll
            for (int i = 0; i < 4; i++) {
#pragma unroll
                for (int r = 0; r < 4; r++) {
                    const int m = m0 + i * 16 + quad * 4 + r;
                    const int bb = m >> 12, seq = m & 4095;
                    dst[((size_t)(bb * 8 + hl) * 4096 + seq) * 64 + d] =
                        f2b((acc[i][j][r] + bs) * scale);
                }
            }
        }
    } else {
        // V: pack 4 consecutive seq into b64 LDS writes, then coalesced b128
#pragma unroll
        for (int j = 0; j < 4; j++) {
            const int jcl = j0 + j * 16 + l15;             // 0..127
            const float bs = bias[nbase + jcl];
#pragma unroll
            for (int i = 0; i < 4; i++) {
                uint2 w;
                w.x = pack2(acc[i][j][0] + bs, acc[i][j][1] + bs);
                w.y = pack2(acc[i][j][2] + bs, acc[i][j][3] + bs);
                *(uint2*)&sT[jcl][(wv >> 1) * 64 + i * 16 + quad * 4] = w;
            }
        }
        __syncthreads();

        const int jcl = tid >> 1, half = tid & 1;
        const int hl = (bis * 128 + jcl) >> 6;
        const int d  = jcl & 63;
        const int bb = (blockIdx.x * 128) >> 12;
        const int seq0 = ((blockIdx.x * 128) & 4095) + half * 64;
        short* dst = Vb + ((size_t)(bb * 8 + hl) * 64 + d) * 4096 + seq0;
#pragma unroll
        for (int u = 0; u < 8; u++)
            *(short8*)(dst + u * 8) = *(const short8*)&sT[jcl][half * 64 + u * 8];
    }
}

// ---------------------------------------------------------------------------
// Flash attention, r21 = r19 structure (dbuf, ONE barrier/tile, o2 row-sum
// on the MFMA pipe, register-P via bit2<->3-swapped V LDS) +
//  (1) WAVE PHASE STAGGER: each wave processes the 4 c-subtiles in rotated
//      order c = (i + wv) & 3. Subtile sums are order-independent, so this
//      is free and register-neutral, but it de-phases the block's waves:
//      at any instant ~half are in QK/PV (MFMA) and half in exp/pack
//      (VALU), converting the r19 pipe ALTERNATION (48.8+44.8 = 94% sum,
//      each pipe half-idle) into overlap.
//  (2) pack2 (3 VALU) -> v_cvt_pk_bf16_f32 (1 VALU) for the P->bf16 pack.
// r20's in-wave 2-deep ST pipeline is REVERTED: it spilled (+12 MB scratch
// traffic, WRITE_SIZE 16.9->25.1 MB) because two live f32x16 STs must sit
// in arch VGPRs (they feed VALU exp, can't hide in AGPRs).
// Split-K=2 partials (no-max streaming softmax): O = (l0*O0+l1*O1)/(l0+l1).
// ---------------------------------------------------------------------------
__global__ __launch_bounds__(512, 4) void flash_attn(
    const short* __restrict__ Q, const short* __restrict__ K,
    const short* __restrict__ V, short* __restrict__ PO0,
    short* __restrict__ PO1, float* __restrict__ lbuf, int niter)
{
    __shared__ short sK[2][128][72];     // [buf][key][d], +8 pad
    __shared__ short sV[2][64][136];     // [buf][d][key-bitswapped], +8 pad

    const int tid  = threadIdx.x;
    const int wv   = tid >> 6;            // 0..7
    const int lane = tid & 63;
    const int l31  = lane & 31;
    const int half = lane >> 5;           // 0/1
    const int bh = blockIdx.y;
    const int b = bh >> 3, h = bh & 7;
    const int qw = blockIdx.x * 256 + wv * 32;   // wave's 32 queries
    const int ks = blockIdx.z;
    const int key0 = ks * niter * 128;

    const short* Qb = Q + (size_t)bh * 4096 * 64;
    const short* Kb = K + (size_t)bh * 4096 * 64;
    const short* Vb = V + (size_t)bh * 64 * 4096;

    // Q B-frags: B[k=d][n=query l31]; step s covers d = s*16 + half*8 + j
    short8 aq[4];
#pragma unroll
    for (int s = 0; s < 4; s++)
        aq[s] = *(const short8*)(Qb + (size_t)(qw + l31) * 64 + s * 16 + half * 8);

    // ones A-frag for the row-sum MFMA (bf16 1.0 = 0x3F80)
    short8 ones;
#pragma unroll
    for (int j = 0; j < 8; j++) ones[j] = (short)0x3F80;

    f32x16 o0 = {}, o1 = {};              // O^T acc, d-tiles 0/1 (col=query)
    f32x16 o2 = {};                       // row-sum acc (any reg = lsum)

    // staging: 512 threads x (2 K-chunks + 2 V-chunks) per 128-key tile
    const int r0  = tid >> 3;             // 0..63
    const int scb = (tid & 7) * 8;        // 0..56
    const int vb  = (scb & ~12) | ((scb & 8) >> 1);  // bit2<->bit3 swap base

    short8 pk0, pk1, pv0, pv1;
    // tile 0 -> buf 0 (no barrier needed yet: LDS untouched)
    pk0 = *(const short8*)(Kb + (size_t)(key0 + r0) * 64 + scb);
    pk1 = *(const short8*)(Kb + (size_t)(key0 + 64 + r0) * 64 + scb);
    pv0 = *(const short8*)(Vb + (size_t)r0 * 4096 + key0 + scb);
    pv1 = *(const short8*)(Vb + (size_t)r0 * 4096 + key0 + 64 + scb);
    *(short8*)&sK[0][r0][scb]      = pk0;
    *(short8*)&sK[0][64 + r0][scb] = pk1;
    *(uint2*)&sV[0][r0][vb]          = ((const uint2*)&pv0)[0];
    *(uint2*)&sV[0][r0][vb + 8]      = ((const uint2*)&pv0)[1];
    *(uint2*)&sV[0][r0][64 + vb]     = ((const uint2*)&pv1)[0];
    *(uint2*)&sV[0][r0][64 + vb + 8] = ((const uint2*)&pv1)[1];
    // prefetch tile 1 into regs
    {
        const int kn = key0 + 128;
        pk0 = *(const short8*)(Kb + (size_t)(kn + r0) * 64 + scb);
        pk1 = *(const short8*)(Kb + (size_t)(kn + 64 + r0) * 64 + scb);
        pv0 = *(const short8*)(Vb + (size_t)r0 * 4096 + kn + scb);
        pv1 = *(const short8*)(Vb + (size_t)r0 * 4096 + kn + 64 + scb);
    }

    for (int kt = 0; kt < niter; ++kt) {
        __syncthreads();   // buf[kt&1] writes visible; prev reads of buf[(kt+1)&1] done

        if (kt + 1 < niter) {          // write tile kt+1 to the other buffer
            short (*sKn)[72]  = sK[(kt + 1) & 1];
            short (*sVn)[136] = sV[(kt + 1) & 1];
            *(short8*)&sKn[r0][scb]      = pk0;
            *(short8*)&sKn[64 + r0][scb] = pk1;
            *(uint2*)&sVn[r0][vb]          = ((const uint2*)&pv0)[0];
            *(uint2*)&sVn[r0][vb + 8]      = ((const uint2*)&pv0)[1];
            *(uint2*)&sVn[r0][64 + vb]     = ((const uint2*)&pv1)[0];
            *(uint2*)&sVn[r0][64 + vb + 8] = ((const uint2*)&pv1)[1];
        }
        if (kt + 2 < niter) {          // issue global loads for tile kt+2
            const int kn = key0 + (kt + 2) * 128;
            pk0 = *(const short8*)(Kb + (size_t)(kn + r0) * 64 + scb);
            pk1 = *(const short8*)(Kb + (size_t)(kn + 64 + r0) * 64 + scb);
            pv0 = *(const short8*)(Vb + (size_t)r0 * 4096 + kn + scb);
            pv1 = *(const short8*)(Vb + (size_t)r0 * 4096 + kn + 64 + scb);
        }

        const short (*sKc)[72]  = sK[kt & 1];
        const short (*sVc)[136] = sV[kt & 1];

        // 4 c-subtiles of 32 keys, WAVE-ROTATED order: c = (i + wv) & 3.
        // S^T C/D: col=query l31, reg r holds key c*32 + (r&3)+8*(r>>2)+4*half
#pragma unroll
        for (int i = 0; i < 4; i++) {
            const int c = (i + wv) & 3;
            f32x16 ST = {};
            __builtin_amdgcn_s_setprio(1);
#pragma unroll
            for (int s = 0; s < 4; s++) {
                const short8 bk = *(const short8*)&sKc[c * 32 + l31][s * 16 + half * 8];
                ST = MFMA32(bk, aq[s], ST);
            }
            __builtin_amdgcn_s_setprio(0);
            float e[16];
#pragma unroll
            for (int r = 0; r < 16; r++) e[r] = EXP2(ST[r]);
            uint4 w0 = { cvtpk(e[0], e[1]),   cvtpk(e[2], e[3]),
                         cvtpk(e[4], e[5]),   cvtpk(e[6], e[7]) };
            uint4 w1 = { cvtpk(e[8], e[9]),   cvtpk(e[10], e[11]),
                         cvtpk(e[12], e[13]), cvtpk(e[14], e[15]) };
            const short8 bp0 = *(const short8*)&w0;   // PV B-frag, step t=2c
            const short8 bp1 = *(const short8*)&w1;   // step t=2c+1

            // O^T += V^T x P^T ; o2 += 1 x P^T (row sums on the MFMA pipe)
            __builtin_amdgcn_s_setprio(1);
            const short8 bv00 = *(const short8*)&sVc[l31][(2 * c) * 16 + half * 8];
            const short8 bv01 = *(const short8*)&sVc[32 + l31][(2 * c) * 16 + half * 8];
            o0 = MFMA32(bv00, bp0, o0);
            o1 = MFMA32(bv01, bp0, o1);
            o2 = MFMA32(ones, bp0, o2);
            const short8 bv10 = *(const short8*)&sVc[l31][(2 * c + 1) * 16 + half * 8];
            const short8 bv11 = *(const short8*)&sVc[32 + l31][(2 * c + 1) * 16 + half * 8];
            o0 = MFMA32(bv10, bp1, o0);
            o1 = MFMA32(bv11, bp1, o1);
            o2 = MFMA32(ones, bp1, o2);
            __builtin_amdgcn_s_setprio(0);
        }
    }

    // o2[0] = full row sum for query l31 (all keys, both halves, all tiles)
    const float lsum = o2[0];
    const float inv = 1.f / fmaxf(lsum, 1e-30f);

    short* PO = (ks == 0) ? PO0 : PO1;
    // O^T: reg-quad q = 4 consecutive d at 8q + 4*half (+32 for o1), query l31
#pragma unroll
    for (int q = 0; q < 4; q++) {
        uint2 w0, w1;
        w0.x = pack2(o0[4 * q + 0] * inv, o0[4 * q + 1] * inv);
        w0.y = pack2(o0[4 * q + 2] * inv, o0[4 * q + 3] * inv);
        w1.x = pack2(o1[4 * q + 0] * inv, o1[4 * q + 1] * inv);
        w1.y = pack2(o1[4 * q + 2] * inv, o1[4 * q + 3] * inv);
        const size_t rowoff = ((size_t)b * 4096 + qw + l31) * 512;
        const int col = h * 64 + q * 8 + half * 4;
        *(uint2*)(PO + rowoff + col) = w0;
        *(uint2*)(PO + rowoff + col + 32) = w1;
    }
    if (half == 0)
        lbuf[((size_t)ks * 16 + bh) * 4096 + qw + l31] = lsum;
}

// ---------------------------------------------------------------------------
// Combine the 2 key-split partials: attn(ws) = (l0*O0 + l1*O1)/(l0+l1).
// ---------------------------------------------------------------------------
__global__ __launch_bounds__(256) void combine(
    const short* __restrict__ PO0, const short* __restrict__ PO1,
    short* __restrict__ attn, const float* __restrict__ L)
{
    const int i = blockIdx.x * 256 + threadIdx.x;   // 0..524287
    const size_t flat = (size_t)i * 8;
    const int col = (int)(flat & 511);
    const int q   = (int)((flat >> 9) & 4095);
    const int b   = (int)(flat >> 21);
    const int bh  = b * 8 + (col >> 6);
    const float l0 = L[(size_t)bh * 4096 + q];
    const float l1 = L[(size_t)65536 + (size_t)bh * 4096 + q];
    const float inv = 1.f / (l0 + l1);
    const float w0 = l0 * inv, w1 = l1 * inv;
    const short8 a = *(const short8*)(PO0 + flat);
    const short8 c = *(const short8*)(PO1 + flat);
    short8 r;
#pragma unroll
    for (int k = 0; k < 8; k += 2) {
        const unsigned p = pack2(w0 * b2f(a[k]) + w1 * b2f(c[k]),
                                 w0 * b2f(a[k + 1]) + w1 * b2f(c[k + 1]));
        r[k]     = (short)(p & 0xFFFF);
        r[k + 1] = (short)(p >> 16);
    }
    *(short8*)(attn + flat) = r;
}

// ---------------------------------------------------------------------------
// Projection, single full-GPU launch: grid (64,4) = 256 blocks.
// ---------------------------------------------------------------------------
__global__ __launch_bounds__(256) void proj_gemm(
    const short* __restrict__ A, const short* __restrict__ W,
    const float* __restrict__ bias, float* __restrict__ dst)
{
    const int tid  = threadIdx.x;
    const int wv   = tid >> 6;
    const int lane = tid & 63;
    const int l15  = lane & 15;
    const int quad = lane >> 4;
    const int m0 = blockIdx.x * 128 + (wv >> 1) * 64;   // 0..8191
    const int n0 = blockIdx.y * 128 + (wv & 1) * 64;

    const f32x4 zero = {0.f, 0.f, 0.f, 0.f};
    f32x4 acc[4][4];
#pragma unroll
    for (int i = 0; i < 4; i++)
#pragma unroll
        for (int j = 0; j < 4; j++) acc[i][j] = zero;

    for (int k0 = 0; k0 < 512; k0 += 32) {
        short8 a[4], b[4];
#pragma unroll
        for (int i = 0; i < 4; i++)
            a[i] = *(const short8*)(A + (size_t)(m0 + i * 16 + l15) * 512 + k0 + quad * 8);
#pragma unroll
        for (int j = 0; j < 4; j++)
            b[j] = *(const short8*)(W + (size_t)(n0 + j * 16 + l15) * 512 + k0 + quad * 8);
#pragma unroll
        for (int i = 0; i < 4; i++)
#pragma unroll
            for (int j = 0; j < 4; j++)
                acc[i][j] = MFMA16(a[i], b[j], acc[i][j]);
    }

#pragma unroll
    for (int j = 0; j < 4; j++) {
        const int n = n0 + j * 16 + l15;
        const float bs = bias[n];
#pragma unroll
        for (int i = 0; i < 4; i++) {
#pragma unroll
            for (int r = 0; r < 4; r++) {
                const int m = m0 + i * 16 + quad * 4 + r;
                dst[(size_t)m * 512 + n] = acc[i][j][r] + bs;
            }
        }
    }
}

// ---------------------------------------------------------------------------
// Memory plan (ws >= 25 MB, proven). 5 dispatches:
//   d_out [0,8M):    xb -> PO0 (flash split 0) -> proj output [0,8M)
//   d_out [8M,9.5M): wb (dead after qkv)
//   d_out [8M,16M):  PO1 (flash split 1) -> proj output [8M,16M)
//   ws [0,8M):  Qf -> attn (combine output; Qf dead after flash)
//   ws [8M,16M) Kf | [16M,24M) Vf | [24M,24.5M) lbuf | [24.5M,25M) pwb
// ---------------------------------------------------------------------------
extern "C" void kernel_launch(void* const* d_in, const int* in_sizes, int n_in,
                              void* d_out, int out_size, void* d_ws, size_t ws_size,
                              hipStream_t stream)
{
    const float* x      = (const float*)d_in[0];   // [2,4096,512] f32
    const float* qkv_w  = (const float*)d_in[1];   // [1536,512]   f32
    const float* qkv_b  = (const float*)d_in[2];   // [1536]       f32
    const float* proj_w = (const float*)d_in[3];   // [512,512]    f32
    const float* proj_b = (const float*)d_in[4];   // [512]        f32

    const size_t MB = 1024 * 1024;
    short* xb   = (short*)d_out;
    short* wb   = (short*)d_out + 4 * MB;
    short* PO0  = (short*)d_out;                   // [0,8M) after xb dies
    short* PO1  = (short*)d_out + 4 * MB;          // [8M,16M) after wb dies
    float* out  = (float*)d_out;

    short* Qf = (short*)d_ws;
    short* Kf = Qf + (size_t)16 * 4096 * 64;
    short* Vf = Kf + (size_t)16 * 4096 * 64;       // [bh][64][4096]
    short* attn = Qf;                              // ws [0,8M), post-flash life
    float* lbuf = (float*)((char*)d_ws + 24 * MB);
    short* pwb  = (short*)((char*)d_ws + 24 * MB + 512 * 1024);

    cvt3<<<2560, 256, 0, stream>>>(x, xb, 524288, qkv_w, wb, 98304, proj_w, pwb, 32768);
    qkv_gemm<<<dim3(64, 12), 256, 0, stream>>>(xb, wb, qkv_b, Qf, Kf, Vf);
    flash_attn<<<dim3(16, 16, 2), 512, 0, stream>>>(Qf, Kf, Vf, PO0, PO1, lbuf, 16);
    combine<<<2048, 256, 0, stream>>>(PO0, PO1, attn, lbuf);
    proj_gemm<<<dim3(64, 4), 256, 0, stream>>>(attn, pwb, proj_b, out);
}

// Round 5
// 230.575 us; speedup vs baseline: 1.0839x; 1.0702x over previous
//
#include <hip/hip_runtime.h>
#include <hip/hip_bf16.h>
#include <stdint.h>
#include <stddef.h>

typedef __attribute__((ext_vector_type(8))) short short8;
typedef __attribute__((ext_vector_type(4))) float f32x4;
typedef __attribute__((ext_vector_type(16))) float f32x16;

#define MFMA16(a, b, c) __builtin_amdgcn_mfma_f32_16x16x32_bf16((a), (b), (c), 0, 0, 0)
#define MFMA32(a, b, c) __builtin_amdgcn_mfma_f32_32x32x16_bf16((a), (b), (c), 0, 0, 0)

// Q pre-scale: HEAD_DIM^-0.5 * log2(e); flash uses raw v_exp_f32 (exp2)
#define QSCALE 0.1803368801111204f

#if __has_builtin(__builtin_amdgcn_exp2f)
#define EXP2(x) __builtin_amdgcn_exp2f(x)
#else
#define EXP2(x) __builtin_exp2f(x)
#endif

__device__ __forceinline__ float b2f(short x) {
    unsigned u = ((unsigned)(unsigned short)x) << 16;
    float f; __builtin_memcpy(&f, &u, 4); return f;
}
// round-nearest-even f32->bf16 (scalar)
__device__ __forceinline__ short f2b(float f) {
    unsigned u; __builtin_memcpy(&u, &f, 4);
    u = (u + 0x7FFFu + ((u >> 16) & 1u)) >> 16;
    return (short)u;
}
// two f32 -> packed bf16x2 in 3 VALU (2 adds + v_perm), round-half-up.
__device__ __forceinline__ unsigned pack2(float a, float b) {
    unsigned ua, ub; __builtin_memcpy(&ua, &a, 4); __builtin_memcpy(&ub, &b, 4);
    return __builtin_amdgcn_perm(ub + 0x8000u, ua + 0x8000u, 0x07060302u);
}
// two f32 -> packed bf16x2 in ONE VALU (RNE). Same lo/hi order as pack2.
__device__ __forceinline__ unsigned cvtpk(float a, float b) {
    unsigned r;
    asm("v_cvt_pk_bf16_f32 %0, %1, %2" : "=v"(r) : "v"(a), "v"(b));
    return r;
}
// 8 contiguous f32 -> bf16x8 (RNE)
__device__ __forceinline__ short8 load8f(const float* p) {
    const float4 f0 = *(const float4*)p;
    const float4 f1 = *(const float4*)(p + 4);
    short8 r;
    r[0]=f2b(f0.x); r[1]=f2b(f0.y); r[2]=f2b(f0.z); r[3]=f2b(f0.w);
    r[4]=f2b(f1.x); r[5]=f2b(f1.y); r[6]=f2b(f1.z); r[7]=f2b(f1.w);
    return r;
}

// ---------------------------------------------------------------------------
// Fused f32->bf16 converter for up to 3 arrays. nX = elems/8.
// ---------------------------------------------------------------------------
__global__ __launch_bounds__(256) void cvt3(
    const float* __restrict__ s0, short* __restrict__ d0, int n0,
    const float* __restrict__ s1, short* __restrict__ d1, int n1,
    const float* __restrict__ s2, short* __restrict__ d2, int n2)
{
    int i = blockIdx.x * 256 + threadIdx.x;
    if (i < n0) { *(short8*)(d0 + (size_t)i * 8) = load8f(s0 + (size_t)i * 8); return; }
    i -= n0;
    if (i < n1) { *(short8*)(d1 + (size_t)i * 8) = load8f(s1 + (size_t)i * 8); return; }
    i -= n1;
    if (i < n2) { *(short8*)(d2 + (size_t)i * 8) = load8f(s2 + (size_t)i * 8); }
}

// ---------------------------------------------------------------------------
// Fused QKV GEMM (bf16 in/out). Grid (64,12): sec = y>>2 (0=Q,1=K,2=V).
//   Q (x QSCALE) -> Qb[bh][seq][64];  K -> Kb[bh][seq][64]
//   V -> Vb[bh][64][seq] via LDS-transposed epilogue (coalesced b128 stores)
// r22: Q/K epilogue ALSO goes through LDS now. The old path did 64 scalar
// 2-byte global stores per thread (scattered, 32B/quad at 128B stride) —
// classic write-amplification. New path mirrors the proven V branch:
// stage f2b((acc+bias)*scale) into sT[seqlocal][jcl] (scalar ds_write_b16,
// 2-way banks = free), barrier, then each thread streams one [seq][64d]
// 128-B row as 8x b128 stores.
// ---------------------------------------------------------------------------
__global__ __launch_bounds__(256) void qkv_gemm(
    const short* __restrict__ X, const short* __restrict__ W,
    const float* __restrict__ bias,
    short* __restrict__ Qb, short* __restrict__ Kb, short* __restrict__ Vb)
{
    __shared__ short sT[128][132];

    const int tid  = threadIdx.x;
    const int wv   = tid >> 6;
    const int lane = tid & 63;
    const int l15  = lane & 15;
    const int quad = lane >> 4;
    const int m0   = blockIdx.x * 128 + (wv >> 1) * 64;
    const int sec  = blockIdx.y >> 2;
    const int bis  = blockIdx.y & 3;
    const int nbase = sec * 512 + bis * 128;
    const int j0   = (wv & 1) * 64;

    const f32x4 zero = {0.f, 0.f, 0.f, 0.f};
    f32x4 acc[4][4];
#pragma unroll
    for (int i = 0; i < 4; i++)
#pragma unroll
        for (int j = 0; j < 4; j++) acc[i][j] = zero;

    for (int k0 = 0; k0 < 512; k0 += 32) {
        short8 a[4], b[4];
#pragma unroll
        for (int i = 0; i < 4; i++)
            a[i] = *(const short8*)(X + (size_t)(m0 + i * 16 + l15) * 512 + k0 + quad * 8);
#pragma unroll
        for (int j = 0; j < 4; j++)
            b[j] = *(const short8*)(W + (size_t)(nbase + j0 + j * 16 + l15) * 512 + k0 + quad * 8);
#pragma unroll
        for (int i = 0; i < 4; i++)
#pragma unroll
            for (int j = 0; j < 4; j++)
                acc[i][j] = MFMA16(a[i], b[j], acc[i][j]);
    }

    if (sec < 2) {
        const float scale = (sec == 0) ? QSCALE : 1.0f;
        short* dst = (sec == 0) ? Qb : Kb;
        // stage into sT[seqlocal][jcl]: 128 seq x 128 section-cols
#pragma unroll
        for (int j = 0; j < 4; j++) {
            const int jcl = j0 + j * 16 + l15;              // 0..127 block-local col
            const float bs = bias[sec * 512 + bis * 128 + jcl];
#pragma unroll
            for (int i = 0; i < 4; i++) {
                const int s0 = (wv >> 1) * 64 + i * 16 + quad * 4;  // seqlocal base
#pragma unroll
                for (int r = 0; r < 4; r++)
                    sT[s0 + r][jcl] = f2b((acc[i][j][r] + bs) * scale);
            }
        }
        __syncthreads();

        // write out: 256 rows (2 hl x 128 seq); thread owns one 128-B row
        const int seqlocal = tid & 127;
        const int hl_loc   = tid >> 7;                      // 0/1
        const int hl  = bis * 2 + hl_loc;
        const int m   = blockIdx.x * 128 + seqlocal;
        const int bb  = m >> 12, seqg = m & 4095;
        short* drow = dst + ((size_t)(bb * 8 + hl) * 4096 + seqg) * 64;
#pragma unroll
        for (int u = 0; u < 8; u++)
            *(short8*)(drow + u * 8) = *(const short8*)&sT[seqlocal][hl_loc * 64 + u * 8];
    } else {
        // V: pack 4 consecutive seq into b64 LDS writes, then coalesced b128
#pragma unroll
        for (int j = 0; j < 4; j++) {
            const int jcl = j0 + j * 16 + l15;             // 0..127
            const float bs = bias[nbase + jcl];
#pragma unroll
            for (int i = 0; i < 4; i++) {
                uint2 w;
                w.x = pack2(acc[i][j][0] + bs, acc[i][j][1] + bs);
                w.y = pack2(acc[i][j][2] + bs, acc[i][j][3] + bs);
                *(uint2*)&sT[jcl][(wv >> 1) * 64 + i * 16 + quad * 4] = w;
            }
        }
        __syncthreads();

        const int jcl = tid >> 1, half = tid & 1;
        const int hl = (bis * 128 + jcl) >> 6;
        const int d  = jcl & 63;
        const int bb = (blockIdx.x * 128) >> 12;
        const int seq0 = ((blockIdx.x * 128) & 4095) + half * 64;
        short* dst = Vb + ((size_t)(bb * 8 + hl) * 64 + d) * 4096 + seq0;
#pragma unroll
        for (int u = 0; u < 8; u++)
            *(short8*)(dst + u * 8) = *(const short8*)&sT[jcl][half * 64 + u * 8];
    }
}

// ---------------------------------------------------------------------------
// Flash attention, r22 = r21 (dbuf, ONE barrier/tile, register-P via
// bit2<->3-swapped V LDS, wave stagger, cvtpk) with o2 DROPPED:
// the 8 ones-MFMA32/tile (20% of MFMA work) move to a 4-accumulator VALU
// TREE (independent adds, no serial chain) + one epilogue __shfl_xor.
// Rationale from r21 counters: VALUBusy 37% (60% headroom) while both
// pipes are half-idle at fixed 4 waves/SIMD — shorten the MFMA critical
// path, spend idle VALU. Also frees 16 acc regs (no spill risk).
// Split-K=2 partials (no-max streaming softmax): O = (l0*O0+l1*O1)/(l0+l1).
// ---------------------------------------------------------------------------
__global__ __launch_bounds__(512, 4) void flash_attn(
    const short* __restrict__ Q, const short* __restrict__ K,
    const short* __restrict__ V, short* __restrict__ PO0,
    short* __restrict__ PO1, float* __restrict__ lbuf, int niter)
{
    __shared__ short sK[2][128][72];     // [buf][key][d], +8 pad
    __shared__ short sV[2][64][136];     // [buf][d][key-bitswapped], +8 pad

    const int tid  = threadIdx.x;
    const int wv   = tid >> 6;            // 0..7
    const int lane = tid & 63;
    const int l31  = lane & 31;
    const int half = lane >> 5;           // 0/1
    const int bh = blockIdx.y;
    const int b = bh >> 3, h = bh & 7;
    const int qw = blockIdx.x * 256 + wv * 32;   // wave's 32 queries
    const int ks = blockIdx.z;
    const int key0 = ks * niter * 128;

    const short* Qb = Q + (size_t)bh * 4096 * 64;
    const short* Kb = K + (size_t)bh * 4096 * 64;
    const short* Vb = V + (size_t)bh * 64 * 4096;

    // Q B-frags: B[k=d][n=query l31]; step s covers d = s*16 + half*8 + j
    short8 aq[4];
#pragma unroll
    for (int s = 0; s < 4; s++)
        aq[s] = *(const short8*)(Qb + (size_t)(qw + l31) * 64 + s * 16 + half * 8);

    f32x16 o0 = {}, o1 = {};              // O^T acc, d-tiles 0/1 (col=query)
    float la0 = 0.f, la1 = 0.f, la2 = 0.f, la3 = 0.f;   // lsum tree partials

    // staging: 512 threads x (2 K-chunks + 2 V-chunks) per 128-key tile
    const int r0  = tid >> 3;             // 0..63
    const int scb = (tid & 7) * 8;        // 0..56
    const int vb  = (scb & ~12) | ((scb & 8) >> 1);  // bit2<->bit3 swap base

    short8 pk0, pk1, pv0, pv1;
    // tile 0 -> buf 0 (no barrier needed yet: LDS untouched)
    pk0 = *(const short8*)(Kb + (size_t)(key0 + r0) * 64 + scb);
    pk1 = *(const short8*)(Kb + (size_t)(key0 + 64 + r0) * 64 + scb);
    pv0 = *(const short8*)(Vb + (size_t)r0 * 4096 + key0 + scb);
    pv1 = *(const short8*)(Vb + (size_t)r0 * 4096 + key0 + 64 + scb);
    *(short8*)&sK[0][r0][scb]      = pk0;
    *(short8*)&sK[0][64 + r0][scb] = pk1;
    *(uint2*)&sV[0][r0][vb]          = ((const uint2*)&pv0)[0];
    *(uint2*)&sV[0][r0][vb + 8]      = ((const uint2*)&pv0)[1];
    *(uint2*)&sV[0][r0][64 + vb]     = ((const uint2*)&pv1)[0];
    *(uint2*)&sV[0][r0][64 + vb + 8] = ((const uint2*)&pv1)[1];
    // prefetch tile 1 into regs
    {
        const int kn = key0 + 128;
        pk0 = *(const short8*)(Kb + (size_t)(kn + r0) * 64 + scb);
        pk1 = *(const short8*)(Kb + (size_t)(kn + 64 + r0) * 64 + scb);
        pv0 = *(const short8*)(Vb + (size_t)r0 * 4096 + kn + scb);
        pv1 = *(const short8*)(Vb + (size_t)r0 * 4096 + kn + 64 + scb);
    }

    for (int kt = 0; kt < niter; ++kt) {
        __syncthreads();   // buf[kt&1] writes visible; prev reads of buf[(kt+1)&1] done

        if (kt + 1 < niter) {          // write tile kt+1 to the other buffer
            short (*sKn)[72]  = sK[(kt + 1) & 1];
            short (*sVn)[136] = sV[(kt + 1) & 1];
            *(short8*)&sKn[r0][scb]      = pk0;
            *(short8*)&sKn[64 + r0][scb] = pk1;
            *(uint2*)&sVn[r0][vb]          = ((const uint2*)&pv0)[0];
            *(uint2*)&sVn[r0][vb + 8]      = ((const uint2*)&pv0)[1];
            *(uint2*)&sVn[r0][64 + vb]     = ((const uint2*)&pv1)[0];
            *(uint2*)&sVn[r0][64 + vb + 8] = ((const uint2*)&pv1)[1];
        }
        if (kt + 2 < niter) {          // issue global loads for tile kt+2
            const int kn = key0 + (kt + 2) * 128;
            pk0 = *(const short8*)(Kb + (size_t)(kn + r0) * 64 + scb);
            pk1 = *(const short8*)(Kb + (size_t)(kn + 64 + r0) * 64 + scb);
            pv0 = *(const short8*)(Vb + (size_t)r0 * 4096 + kn + scb);
            pv1 = *(const short8*)(Vb + (size_t)r0 * 4096 + kn + 64 + scb);
        }

        const short (*sKc)[72]  = sK[kt & 1];
        const short (*sVc)[136] = sV[kt & 1];

        // 4 c-subtiles of 32 keys, WAVE-ROTATED order: c = (i + wv) & 3.
        // S^T C/D: col=query l31, reg r holds key c*32 + (r&3)+8*(r>>2)+4*half
#pragma unroll
        for (int i = 0; i < 4; i++) {
            const int c = (i + wv) & 3;
            f32x16 ST = {};
            __builtin_amdgcn_s_setprio(1);
#pragma unroll
            for (int s = 0; s < 4; s++) {
                const short8 bk = *(const short8*)&sKc[c * 32 + l31][s * 16 + half * 8];
                ST = MFMA32(bk, aq[s], ST);
            }
            __builtin_amdgcn_s_setprio(0);
            float e[16];
#pragma unroll
            for (int r = 0; r < 16; r++) e[r] = EXP2(ST[r]);
            la0 += (e[0] + e[1]) + (e[2] + e[3]);
            la1 += (e[4] + e[5]) + (e[6] + e[7]);
            la2 += (e[8] + e[9]) + (e[10] + e[11]);
            la3 += (e[12] + e[13]) + (e[14] + e[15]);
            uint4 w0 = { cvtpk(e[0], e[1]),   cvtpk(e[2], e[3]),
                         cvtpk(e[4], e[5]),   cvtpk(e[6], e[7]) };
            uint4 w1 = { cvtpk(e[8], e[9]),   cvtpk(e[10], e[11]),
                         cvtpk(e[12], e[13]), cvtpk(e[14], e[15]) };
            const short8 bp0 = *(const short8*)&w0;   // PV B-frag, step t=2c
            const short8 bp1 = *(const short8*)&w1;   // step t=2c+1

            // O^T += V^T x P^T : A=V^T[d][key] from bit-swapped LDS
            __builtin_amdgcn_s_setprio(1);
            const short8 bv00 = *(const short8*)&sVc[l31][(2 * c) * 16 + half * 8];
            const short8 bv01 = *(const short8*)&sVc[32 + l31][(2 * c) * 16 + half * 8];
            o0 = MFMA32(bv00, bp0, o0);
            o1 = MFMA32(bv01, bp0, o1);
            const short8 bv10 = *(const short8*)&sVc[l31][(2 * c + 1) * 16 + half * 8];
            const short8 bv11 = *(const short8*)&sVc[32 + l31][(2 * c + 1) * 16 + half * 8];
            o0 = MFMA32(bv10, bp1, o0);
            o1 = MFMA32(bv11, bp1, o1);
            __builtin_amdgcn_s_setprio(0);
        }
    }

    // lane's half-row sum; partner half (lane^32) holds the other 16 keys/c
    float lsum = (la0 + la1) + (la2 + la3);
    lsum += __shfl_xor(lsum, 32);
    const float inv = 1.f / fmaxf(lsum, 1e-30f);

    short* PO = (ks == 0) ? PO0 : PO1;
    // O^T: reg-quad q = 4 consecutive d at 8q + 4*half (+32 for o1), query l31
#pragma unroll
    for (int q = 0; q < 4; q++) {
        uint2 w0, w1;
        w0.x = pack2(o0[4 * q + 0] * inv, o0[4 * q + 1] * inv);
        w0.y = pack2(o0[4 * q + 2] * inv, o0[4 * q + 3] * inv);
        w1.x = pack2(o1[4 * q + 0] * inv, o1[4 * q + 1] * inv);
        w1.y = pack2(o1[4 * q + 2] * inv, o1[4 * q + 3] * inv);
        const size_t rowoff = ((size_t)b * 4096 + qw + l31) * 512;
        const int col = h * 64 + q * 8 + half * 4;
        *(uint2*)(PO + rowoff + col) = w0;
        *(uint2*)(PO + rowoff + col + 32) = w1;
    }
    if (half == 0)
        lbuf[((size_t)ks * 16 + bh) * 4096 + qw + l31] = lsum;
}

// ---------------------------------------------------------------------------
// Combine the 2 key-split partials: attn(ws) = (l0*O0 + l1*O1)/(l0+l1).
// ---------------------------------------------------------------------------
__global__ __launch_bounds__(256) void combine(
    const short* __restrict__ PO0, const short* __restrict__ PO1,
    short* __restrict__ attn, const float* __restrict__ L)
{
    const int i = blockIdx.x * 256 + threadIdx.x;   // 0..524287
    const size_t flat = (size_t)i * 8;
    const int col = (int)(flat & 511);
    const int q   = (int)((flat >> 9) & 4095);
    const int b   = (int)(flat >> 21);
    const int bh  = b * 8 + (col >> 6);
    const float l0 = L[(size_t)bh * 4096 + q];
    const float l1 = L[(size_t)65536 + (size_t)bh * 4096 + q];
    const float inv = 1.f / (l0 + l1);
    const float w0 = l0 * inv, w1 = l1 * inv;
    const short8 a = *(const short8*)(PO0 + flat);
    const short8 c = *(const short8*)(PO1 + flat);
    short8 r;
#pragma unroll
    for (int k = 0; k < 8; k += 2) {
        const unsigned p = pack2(w0 * b2f(a[k]) + w1 * b2f(c[k]),
                                 w0 * b2f(a[k + 1]) + w1 * b2f(c[k + 1]));
        r[k]     = (short)(p & 0xFFFF);
        r[k + 1] = (short)(p >> 16);
    }
    *(short8*)(attn + flat) = r;
}

// ---------------------------------------------------------------------------
// Projection, single full-GPU launch: grid (64,4) = 256 blocks.
// ---------------------------------------------------------------------------
__global__ __launch_bounds__(256) void proj_gemm(
    const short* __restrict__ A, const short* __restrict__ W,
    const float* __restrict__ bias, float* __restrict__ dst)
{
    const int tid  = threadIdx.x;
    const int wv   = tid >> 6;
    const int lane = tid & 63;
    const int l15  = lane & 15;
    const int quad = lane >> 4;
    const int m0 = blockIdx.x * 128 + (wv >> 1) * 64;   // 0..8191
    const int n0 = blockIdx.y * 128 + (wv & 1) * 64;

    const f32x4 zero = {0.f, 0.f, 0.f, 0.f};
    f32x4 acc[4][4];
#pragma unroll
    for (int i = 0; i < 4; i++)
#pragma unroll
        for (int j = 0; j < 4; j++) acc[i][j] = zero;

    for (int k0 = 0; k0 < 512; k0 += 32) {
        short8 a[4], b[4];
#pragma unroll
        for (int i = 0; i < 4; i++)
            a[i] = *(const short8*)(A + (size_t)(m0 + i * 16 + l15) * 512 + k0 + quad * 8);
#pragma unroll
        for (int j = 0; j < 4; j++)
            b[j] = *(const short8*)(W + (size_t)(n0 + j * 16 + l15) * 512 + k0 + quad * 8);
#pragma unroll
        for (int i = 0; i < 4; i++)
#pragma unroll
            for (int j = 0; j < 4; j++)
                acc[i][j] = MFMA16(a[i], b[j], acc[i][j]);
    }

#pragma unroll
    for (int j = 0; j < 4; j++) {
        const int n = n0 + j * 16 + l15;
        const float bs = bias[n];
#pragma unroll
        for (int i = 0; i < 4; i++) {
#pragma unroll
            for (int r = 0; r < 4; r++) {
                const int m = m0 + i * 16 + quad * 4 + r;
                dst[(size_t)m * 512 + n] = acc[i][j][r] + bs;
            }
        }
    }
}

// ---------------------------------------------------------------------------
// Memory plan (ws >= 25 MB, proven). 5 dispatches:
//   d_out [0,8M):    xb -> PO0 (flash split 0) -> proj output [0,8M)
//   d_out [8M,9.5M): wb (dead after qkv)
//   d_out [8M,16M):  PO1 (flash split 1) -> proj output [8M,16M)
//   ws [0,8M):  Qf -> attn (combine output; Qf dead after flash)
//   ws [8M,16M) Kf | [16M,24M) Vf | [24M,24.5M) lbuf | [24.5M,25M) pwb
// ---------------------------------------------------------------------------
extern "C" void kernel_launch(void* const* d_in, const int* in_sizes, int n_in,
                              void* d_out, int out_size, void* d_ws, size_t ws_size,
                              hipStream_t stream)
{
    const float* x      = (const float*)d_in[0];   // [2,4096,512] f32
    const float* qkv_w  = (const float*)d_in[1];   // [1536,512]   f32
    const float* qkv_b  = (const float*)d_in[2];   // [1536]       f32
    const float* proj_w = (const float*)d_in[3];   // [512,512]    f32
    const float* proj_b = (const float*)d_in[4];   // [512]        f32

    const size_t MB = 1024 * 1024;
    short* xb   = (short*)d_out;
    short* wb   = (short*)d_out + 4 * MB;
    short* PO0  = (short*)d_out;                   // [0,8M) after xb dies
    short* PO1  = (short*)d_out + 4 * MB;          // [8M,16M) after wb dies
    float* out  = (float*)d_out;

    short* Qf = (short*)d_ws;
    short* Kf = Qf + (size_t)16 * 4096 * 64;
    short* Vf = Kf + (size_t)16 * 4096 * 64;       // [bh][64][4096]
    short* attn = Qf;                              // ws [0,8M), post-flash life
    float* lbuf = (float*)((char*)d_ws + 24 * MB);
    short* pwb  = (short*)((char*)d_ws + 24 * MB + 512 * 1024);

    cvt3<<<2560, 256, 0, stream>>>(x, xb, 524288, qkv_w, wb, 98304, proj_w, pwb, 32768);
    qkv_gemm<<<dim3(64, 12), 256, 0, stream>>>(xb, wb, qkv_b, Qf, Kf, Vf);
    flash_attn<<<dim3(16, 16, 2), 512, 0, stream>>>(Qf, Kf, Vf, PO0, PO1, lbuf, 16);
    combine<<<2048, 256, 0, stream>>>(PO0, PO1, attn, lbuf);
    proj_gemm<<<dim3(64, 4), 256, 0, stream>>>(attn, pwb, proj_b, out);
}